// Round 8
// baseline (606.762 us; speedup 1.0000x reference)
//
#include <hip/hip_runtime.h>

// BasalGanglia fused kernel (MI355X / gfx950).
// R12 (resubmit; previous round was an infra container failure — R3 had the
// same signature and cleared on identical resubmit).
// R12 = R11 with the register cap fixed. R11 post-mortem: occupancy DID reach
// 43% (2 blocks/CU via 65KB LDS) but __launch_bounds__(512,4) has min-BLOCKS
// semantics on this toolchain: 4 blocks*8 waves = 8 waves/EU -> 64-VGPR cap ->
// spill (VGPR_Count 64, WRITE_SIZE 15MB). Empirical: (512,2) -> 128-reg cap,
// no spill (R6/R9: 128/112). At VGPR<=128 HW allows 4 waves/SIMD, so LDS and
// VGPR both permit 2 blocks/CU. Single change vs R11: launch_bounds (512,4)->(512,2).
//  - BM 16, grid 512, LDS ~65KB => 2 independent blocks/CU (latency hiding
//    across blocks, no barrier lockstep).
//  - Ws regs 120 -> 40: tiles 0-7 register-resident; tiles 8-20 streamed as
//    MFMA-ready f16 frags from d_ws (prep_frags pre-kernel), riding VMEM/L2.
//  - Keeps R9 wins: acc-carry 2*xstn, permuted whh -> 1-b128 LSTM gates,
//    lstmc pack, 3 barriers/iter.

typedef _Float16 f16_t;
typedef _Float16 f16x8 __attribute__((ext_vector_type(8)));
typedef _Float16 f16x4 __attribute__((ext_vector_type(4)));
typedef float floatx4 __attribute__((ext_vector_type(4)));
typedef float floatx2 __attribute__((ext_vector_type(2)));

#define BTOT 8192
#define BM   16
#define NTHR 512
#define NBLK (BTOT / BM)   // 512 -> 2 blocks/CU
#define VSTR 328           // f16 stride; dword-stride 164 -> uniform bank groups
#define XST  32            // xgpe/hxf row stride (f16), k-pad zeroed
#define NFRAG (21 * 10 * 512)  // d_ws f16 elems: [t][c][lane][8]

struct Params {
  const float *stimulus, *deltavf, *hx0, *cx0;
  const float *w_vf0, *b_vf0, *w_vf1, *b_vf1, *w_vf2, *b_vf2, *w_vf3, *b_vf3;
  const float *w_jd1, *b_jd1, *w_jd2, *b_jd2, *w_kd1, *b_kd1, *w_kd2, *b_kd2;
  const float *w_sg, *b_sg, *w_gs, *b_gs, *w_glat, *b_glat, *w_slat, *b_slat;
  const float *w_d1gpi, *b_d1gpi, *w_stngpi, *b_stngpi;
  const float *w_ih, *b_ih, *w_hh, *b_hh;
  const f16_t* wfrag;   // d_ws: streamed A-frags
  float* out;
};

struct __align__(16) Smem {
  f16_t vstn[BM * VSTR];        // 10496 B
  f16_t xgpe[2][BM * XST];      // 2048 (double buffer)
  f16_t hxf[BM * XST];          // 1024
  f16_t wB2[21 * 512];          // 21504: t<19 gs-frag, t=19/20 glat-frag
  f16_t wsp[10 * 512];          // 10240: stngpi frags
  f16_t whh[5 * 512];           // 5120: w_hh gate frags (row-permuted r'=4j+g)
  union { float h1f[BM * 128]; float scr[1600]; float gates[BM * 80]; } u; // 8192
  float h0f[BM * 64];           // 4096
  float V_D2f[BM * 20];         // 1280
  float lstmc[20][12];          // 960
  float bsumS[304];             // b_slat+b_gs, pad->0
  float bsg[20];                // b_sg+b_glat
  float DPs[BM * 2], vgpis[BM * 2], lamS[BM];
};                              // ~65 KB -> 2 blocks/CU

__device__ __forceinline__ float rcp_f(float x) { return __builtin_amdgcn_rcpf(x); }
__device__ __forceinline__ float sigm_fast(float x) { return rcp_f(1.f + __expf(-x)); }
__device__ __forceinline__ float tanh_fast(float x) { return 1.f - 2.f * rcp_f(1.f + __expf(2.f * x)); }

// 8 f32 weights row[k0..k0+7] -> f16x8, zero for k>=kmax (4-granular).
__device__ __forceinline__ f16x8 ldfrag(const float* row, int k0, int kmax) {
  float4 z = make_float4(0.f, 0.f, 0.f, 0.f);
  int nv = kmax - k0;
  float4 f0 = (nv >= 4) ? *(const float4*)(row + k0) : z;
  float4 f1 = (nv >= 8) ? *(const float4*)(row + k0 + 4) : z;
  f16x8 r;
  r[0] = (f16_t)f0.x; r[1] = (f16_t)f0.y; r[2] = (f16_t)f0.z; r[3] = (f16_t)f0.w;
  r[4] = (f16_t)f1.x; r[5] = (f16_t)f1.y; r[6] = (f16_t)f1.z; r[7] = (f16_t)f1.w;
  return r;
}

// ---- pre-kernel: build streamed A-frags in d_ws ----
// layout: f16 idx = t*5120 + c*512 + lane*8 + jj ; t in [0,21)
// t<19: slat tile rows n=t*16+cl ; t=19/20: sg rows g=(t-19)*16+cl.
// frag element (lane,jj): row cl=lane&15, k = c*32 + (lane>>4)*8 + jj.
__global__ void prep_frags(const float* __restrict__ slat,
                           const float* __restrict__ sg,
                           f16_t* __restrict__ dst) {
  int i = blockIdx.x * blockDim.x + threadIdx.x;
  if (i >= NFRAG) return;
  int t = i / 5120, rem = i - t * 5120;
  int c = rem >> 9, l2 = (rem >> 3) & 63, jj = i & 7;
  int cl = l2 & 15, q = l2 >> 4;
  int k = c * 32 + q * 8 + jj;
  float v = 0.f;
  if (t < 19) { int n = t * 16 + cl; if (n < 300 && k < 300) v = slat[n * 300 + k]; }
  else        { int g = (t - 19) * 16 + cl; if (g < 20 && k < 300) v = sg[(size_t)g * 300 + k]; }
  dst[i] = (f16_t)v;
}

__global__ __launch_bounds__(NTHR, 2) void bg_main(Params P) {
  __shared__ Smem S;
  const int tid  = threadIdx.x;
  const int lane = tid & 63;
  const int wv   = tid >> 6;
  const int q    = lane >> 4;
  const int cl   = lane & 15;
  const int row0 = blockIdx.x * BM;
  const floatx4 zf = {0.f, 0.f, 0.f, 0.f};

  // ================= init + LDS weight-frag staging =================
  if (tid < BM) S.lamS[tid] = sigm_fast(P.deltavf[row0 + tid]);
  for (int i = tid; i < BM * 2; i += NTHR) S.vgpis[i] = 0.f;
  for (int i = tid; i < 2 * BM * XST; i += NTHR) ((f16_t*)S.xgpe)[i] = (f16_t)0.f;
  for (int i = tid; i < BM * XST; i += NTHR) {
    int m = i >> 5, j = i & 31;
    S.hxf[i] = (j < 20) ? (f16_t)P.hx0[(size_t)(row0 + m) * 20 + j] : (f16_t)0.f;
  }
  for (int i = tid; i < BM * VSTR; i += NTHR) S.vstn[i] = (f16_t)0.f;
  for (int i = tid; i < 21 * 512; i += NTHR) {        // gs / glat frags
    int t = i >> 9, l = (i >> 3) & 63, jj = i & 7;
    int c2 = l & 15, k = ((l >> 4) << 3) + jj;
    float v = 0.f;
    if (t < 19) { int n = t * 16 + c2; if (n < 300 && k < 20) v = P.w_gs[n * 20 + k]; }
    else        { int g = (t - 19) * 16 + c2; if (g < 20 && k < 20) v = P.w_glat[g * 20 + k]; }
    S.wB2[i] = (f16_t)v;
  }
  for (int i = tid; i < 10 * 512; i += NTHR) {        // stngpi frags
    int c = i >> 9, l = (i >> 3) & 63, jj = i & 7;
    int p = l & 15, k = c * 32 + ((l >> 4) << 3) + jj;
    float v = (p < 2 && k < 300) ? P.w_stngpi[p * 300 + k] : 0.f;
    S.wsp[i] = (f16_t)v;
  }
  for (int i = tid; i < 5 * 512; i += NTHR) {         // w_hh gate frags, PERMUTED
    int t = i >> 9, l = (i >> 3) & 63, jj = i & 7;
    int c2 = l & 15, k = ((l >> 4) << 3) + jj;
    int orig = (c2 & 3) * 20 + 4 * t + (c2 >> 2);     // r'=4j+g -> orig g*20+j
    S.whh[i] = (f16_t)((k < 20) ? P.w_hh[orig * 20 + k] : 0.f);
  }
  for (int i = tid; i < 240; i += NTHR) {             // LSTM consts [j][12]
    int j = i / 12, c = i - j * 12;
    float v;
    if (c < 4)      v = P.b_ih[c * 20 + j] + P.b_hh[c * 20 + j];
    else if (c < 8) v = P.w_ih[((c - 4) * 20 + j) * 2 + 0];
    else            v = P.w_ih[((c - 8) * 20 + j) * 2 + 1];
    S.lstmc[j][c] = v;
  }
  for (int i = tid; i < 304; i += NTHR) S.bsumS[i] = (i < 300) ? (P.b_slat[i] + P.b_gs[i]) : 0.f;
  for (int i = tid; i < 20; i += NTHR)  S.bsg[i] = P.b_sg[i] + P.b_glat[i];

  { // h0 = relu(stim @ w_vf0^T + b): 16 rows x 64 out; 2 rows/thread
    int o = tid & 63, mb = (tid >> 6) * 2;
    const float4* wr = (const float4*)(P.w_vf0 + o * 300);
    float bias = P.b_vf0[o], a[2];
    a[0] = bias; a[1] = bias;
    for (int kq = 0; kq < 75; ++kq) {
      float4 w = wr[kq];
#pragma unroll
      for (int u = 0; u < 2; ++u) {
        float4 v = *(const float4*)(P.stimulus + (size_t)(row0 + mb + u) * 300 + kq * 4);
        a[u] = fmaf(v.x, w.x, a[u]); a[u] = fmaf(v.y, w.y, a[u]);
        a[u] = fmaf(v.z, w.z, a[u]); a[u] = fmaf(v.w, w.w, a[u]);
      }
    }
#pragma unroll
    for (int u = 0; u < 2; ++u) S.h0f[(mb + u) * 64 + o] = fmaxf(a[u], 0.f);
  }
  __syncthreads();
  { // h1: 16 x 128; 4 rows/thread
    int o = tid & 127, mb = (tid >> 7) * 4;
    const float* wr = P.w_vf1 + o * 64;
    float bias = P.b_vf1[o], a[4];
#pragma unroll
    for (int u = 0; u < 4; ++u) a[u] = bias;
    for (int k = 0; k < 64; ++k) {
      float w = wr[k];
#pragma unroll
      for (int u = 0; u < 4; ++u) a[u] = fmaf(S.h0f[(mb + u) * 64 + k], w, a[u]);
    }
#pragma unroll
    for (int u = 0; u < 4; ++u) S.u.h1f[(mb + u) * 128 + o] = fmaxf(a[u], 0.f);
  }
  __syncthreads();
  { // h2 -> h0f: 16 x 64; 2 rows/thread
    int o = tid & 63, mb = (tid >> 6) * 2;
    const float* wr = P.w_vf2 + o * 128;
    float bias = P.b_vf2[o], a[2];
    a[0] = bias; a[1] = bias;
    for (int k = 0; k < 128; ++k) {
      float w = wr[k];
#pragma unroll
      for (int u = 0; u < 2; ++u) a[u] = fmaf(S.u.h1f[(mb + u) * 128 + k], w, a[u]);
    }
#pragma unroll
    for (int u = 0; u < 2; ++u) S.h0f[(mb + u) * 64 + o] = fmaxf(a[u], 0.f);
  }
  __syncthreads();
  { // drives -> scr[0:1280); vt output
    int oid = tid & 127, mb = (tid >> 7) * 4;
    if (oid < 80) {
      int which = oid / 20, o = oid - which * 20;
      const float *wp, *bp;
      if (which == 0)      { wp = P.w_jd1; bp = P.b_jd1; }
      else if (which == 1) { wp = P.w_jd2; bp = P.b_jd2; }
      else if (which == 2) { wp = P.w_kd1; bp = P.b_kd1; }
      else                 { wp = P.w_kd2; bp = P.b_kd2; }
      float bias = bp[o], a[4];
#pragma unroll
      for (int u = 0; u < 4; ++u) a[u] = bias;
      for (int kq = 0; kq < 75; ++kq) {
        float4 w = *(const float4*)(wp + o * 300 + kq * 4);
#pragma unroll
        for (int u = 0; u < 4; ++u) {
          float4 v = *(const float4*)(P.stimulus + (size_t)(row0 + mb + u) * 300 + kq * 4);
          a[u] = fmaf(v.x, w.x, a[u]); a[u] = fmaf(v.y, w.y, a[u]);
          a[u] = fmaf(v.z, w.z, a[u]); a[u] = fmaf(v.w, w.w, a[u]);
        }
      }
#pragma unroll
      for (int u = 0; u < 4; ++u) S.u.scr[which * 320 + (mb + u) * 20 + o] = a[u];
    }
    if (tid < BM) {
      float a = P.b_vf3[0];
      for (int k = 0; k < 64; ++k) a = fmaf(S.h0f[tid * 64 + k], P.w_vf3[k], a);
      P.out[(size_t)BTOT * 20 + row0 + tid] = tanh_fast(a);
    }
  }
  __syncthreads();
  for (int i = tid; i < BM * 20; i += NTHR) { // FF -> V_D1 scr[1280:), V_D2f
    int m = i / 20;
    float j1 = S.u.scr[i],       j2 = S.u.scr[320 + i];
    float k1 = S.u.scr[640 + i], k2 = S.u.scr[960 + i];
    float L = S.lamS[m], v1 = 0.f, v2 = 0.f;
    for (int s = 0; s < 20; ++s) {
      v1 = sigm_fast(L * (j1 * (1.f - v1) + (1.f - k1) * v1));
      v2 = sigm_fast(L * (j2 * (1.f - v2) + (1.f - k2) * v2));
    }
    S.u.scr[1280 + i] = v1;
    S.V_D2f[i] = v2;
  }
  __syncthreads();
  if (tid < BM * 2) { // V_GPi_DP
    int m = tid >> 1, p2 = tid & 1;
    float a = P.b_d1gpi[p2];
    for (int o = 0; o < 20; ++o) a = fmaf(S.u.scr[1280 + m * 20 + o], P.w_d1gpi[p2 * 20 + o], a);
    S.DPs[tid] = a;
  }
  __syncthreads();

  // ========== slot map: t = wv + 8j. slot0 (t=0-7) register-resident; ==========
  // slot1 (t=8-15) and slot2 (t=16-20, wv<5; 19/20=sg for wv 3/4) streamed.
  f16x8 Ws0[10];
  {
    int n = wv * 16 + cl;   // < 128, always valid slat row
    const float* a0 = P.w_slat + (size_t)n * 300;
#pragma unroll
    for (int c = 0; c < 10; ++c) Ws0[c] = ldfrag(a0, c * 32 + q * 8, 300);
  }
  const f16x8* __restrict__ WG = (const f16x8*)P.wfrag;  // [(t*10+c)*64 + lane]
  const int t1 = 8 + wv;
  const int t2 = 16 + wv;            // valid if wv<5
  const bool has2 = (wv < 5);
  const bool isSgW = (wv == 3 || wv == 4);   // slot2 is sg tile
  const float lamB = S.lamS[cl];
  const float bstn0 = P.b_stngpi[0], bstn1 = P.b_stngpi[1];
  // LSTM: tid<320 owns elem (m0, j0)
  const bool lown = (tid < BM * 20);
  const int  m0 = lown ? tid / 20 : 0;
  const int  j0 = tid - m0 * 20;
  float cxr0 = lown ? P.cx0[(size_t)(row0 + m0) * 20 + j0] : 0.f;
  float hxr0 = 0.f;

  // acc carries 2*xstn across iterations (slat slots); sg slot re-zeroed.
  floatx4 acc[3];
  acc[0] = zf; acc[1] = zf; acc[2] = zf;

  // ================= STN recurrence, 50 iterations, 3 barriers/iter =========
  for (int it = 0; it < 50; ++it) {
    const int po = it & 1, pn = po ^ 1;
    if (isSgW) acc[2] = zf;   // sg slot fresh each iter

    // ---- Phase A: acc += [slat|sg] @ vstn^T (+ glat @ xgpe_old^T, pack) ----
    __builtin_amdgcn_s_setprio(1);
#pragma unroll
    for (int c = 0; c < 10; ++c) {
      f16x8 b0 = *(const f16x8*)&S.vstn[cl * VSTR + c * 32 + q * 8];
      acc[0] = __builtin_amdgcn_mfma_f32_16x16x32_f16(Ws0[c], b0, acc[0], 0, 0, 0);
      f16x8 a1 = WG[(t1 * 10 + c) * 64 + lane];
      acc[1] = __builtin_amdgcn_mfma_f32_16x16x32_f16(a1, b0, acc[1], 0, 0, 0);
      if (has2) {
        f16x8 a2 = WG[(t2 * 10 + c) * 64 + lane];
        acc[2] = __builtin_amdgcn_mfma_f32_16x16x32_f16(a2, b0, acc[2], 0, 0, 0);
      }
    }
    __builtin_amdgcn_s_setprio(0);
    if (isSgW) {
      f16x8 Wg = *(const f16x8*)&S.wB2[(wv + 16) * 512 + lane * 8];
      f16x8 g0 = *(const f16x8*)&S.xgpe[po][cl * XST + q * 8];
      acc[2] = __builtin_amdgcn_mfma_f32_16x16x32_f16(Wg, g0, acc[2], 0, 0, 0);
      int g0i = (wv - 3) * 16 + q * 4;
      if (g0i < 20) {
        floatx4 bg4 = *(const floatx4*)&S.bsg[g0i];
        floatx4 vd4 = *(const floatx4*)&S.V_D2f[cl * 20 + g0i];
        f16x4 pk;
#pragma unroll
        for (int r = 0; r < 4; ++r) pk[r] = (f16_t)(acc[2][r] + bg4[r] - vd4[r]);
        *(f16x4*)&S.xgpe[pn][cl * XST + g0i] = pk;
      }
    }
    __syncthreads(); // b1: xgpe_new ready

    // ---- Phase B: acc += gs @ xgpe_new^T; hh-gates; xstn/vstn update ----
    {
      f16x8 x0 = *(const f16x8*)&S.xgpe[pn][cl * XST + q * 8];
      if (wv < 5) { // hh-gates (permuted rows): gates[batch][4j+g]
        f16x8 Wh = *(const f16x8*)&S.whh[wv * 512 + lane * 8];
        f16x8 hv = *(const f16x8*)&S.hxf[cl * XST + q * 8];
        floatx4 gA = __builtin_amdgcn_mfma_f32_16x16x32_f16(Wh, hv, zf, 0, 0, 0);
        *(floatx4*)&S.u.gates[cl * 80 + wv * 16 + q * 4] = gA;
      }
#pragma unroll
      for (int j = 0; j < 3; ++j) {
        int t = wv + 8 * j;
        if (t < 19) {
          f16x8 Wg = *(const f16x8*)&S.wB2[t * 512 + lane * 8];
          acc[j] = __builtin_amdgcn_mfma_f32_16x16x32_f16(Wg, x0, acc[j], 0, 0, 0);
        }
      }
#pragma unroll
      for (int j = 0; j < 3; ++j) {
        int t = wv + 8 * j;
        if (t < 19) {
          int n0 = t * 16 + q * 4;
          if (!(t == 18 && q == 3)) {  // n0..n0+3 all < 300
            floatx4 bs4 = *(const floatx4*)&S.bsumS[n0];
            f16x4 pk;
#pragma unroll
            for (int r = 0; r < 4; ++r) {
              float tmp = acc[j][r] + bs4[r];      // = 2*xo + W.v + bs
              float xn  = tmp * (1.0f / 3.0f);     // new xstn
              acc[j][r] = tmp * (2.0f / 3.0f);     // carry 2*xn
              pk[r] = (f16_t)tanh_fast(lamB * xn);
            }
            *(f16x4*)&S.vstn[cl * VSTR + n0] = pk;
          }
        }
      }
    }
    __syncthreads(); // b2: vstn_new + gates ready

    // ---- Phase C: wave5 stngpi -> vgpi ----
    if (wv == 5) {
      floatx4 ip0 = zf;
#pragma unroll
      for (int c = 0; c < 10; ++c) {
        f16x8 Wp = *(const f16x8*)&S.wsp[c * 512 + lane * 8];
        f16x8 b0 = *(const f16x8*)&S.vstn[cl * VSTR + c * 32 + q * 8];
        ip0 = __builtin_amdgcn_mfma_f32_16x16x32_f16(Wp, b0, ip0, 0, 0, 0);
      }
      if (q == 0) {
        floatx2 vg = *(const floatx2*)&S.vgpis[cl * 2];
        floatx2 dp = *(const floatx2*)&S.DPs[cl * 2];
        float ipa = lamB * (ip0[0] + bstn0);
        float ipb = lamB * (ip0[1] + bstn1);
        vg[0] = vg[0] + 0.1f * (-vg[0] - dp[0] + 2.f * ipa);
        vg[1] = vg[1] + 0.1f * (-vg[1] - dp[1] + 2.f * ipb);
        *(floatx2*)&S.vgpis[cl * 2] = vg;
      }
    }
    __syncthreads(); // b3: vgpis ready

    // ---- Phase D: LSTM pointwise (1 b128 gates + 3 b128 consts + 1 b64) ----
    if (lown) {
      floatx4 g4 = *(const floatx4*)&S.u.gates[m0 * 80 + j0 * 4];
      floatx4 cb = *(const floatx4*)&S.lstmc[j0][0];
      floatx4 w0 = *(const floatx4*)&S.lstmc[j0][4];
      floatx4 w1 = *(const floatx4*)&S.lstmc[j0][8];
      floatx2 vg = *(const floatx2*)&S.vgpis[m0 * 2];
      float gi = g4[0] + cb[0] - w0[0] * vg[0] - w1[0] * vg[1];
      float gf = g4[1] + cb[1] - w0[1] * vg[0] - w1[1] * vg[1];
      float gg = g4[2] + cb[2] - w0[2] * vg[0] - w1[2] * vg[1];
      float go = g4[3] + cb[3] - w0[3] * vg[0] - w1[3] * vg[1];
      float cn = sigm_fast(gf) * cxr0 + sigm_fast(gi) * tanh_fast(gg);
      cxr0 = cn;
      hxr0 = sigm_fast(go) * tanh_fast(cn);
      S.hxf[m0 * XST + j0] = (f16_t)hxr0;
    }
    // no b4: D writes hxf (next reader B's hh, after next b1); D reads
    // gates/vgpis (next writers B/C, after next b1/b2). Next A touches only
    // vstn/xgpe/Ws (ordered by b2/b1).
  }

  // ---- output hx from registers ----
  if (lown) P.out[(size_t)(row0 + m0) * 20 + j0] = hxr0;
}

extern "C" void kernel_launch(void* const* d_in, const int* in_sizes, int n_in,
                              void* d_out, int out_size, void* d_ws, size_t ws_size,
                              hipStream_t stream) {
  (void)in_sizes; (void)n_in; (void)out_size; (void)ws_size;
  Params P;
  P.stimulus = (const float*)d_in[0];
  P.deltavf  = (const float*)d_in[1];
  P.hx0 = (const float*)d_in[2];
  P.cx0 = (const float*)d_in[3];
  P.w_vf0 = (const float*)d_in[4];  P.b_vf0 = (const float*)d_in[5];
  P.w_vf1 = (const float*)d_in[6];  P.b_vf1 = (const float*)d_in[7];
  P.w_vf2 = (const float*)d_in[8];  P.b_vf2 = (const float*)d_in[9];
  P.w_vf3 = (const float*)d_in[10]; P.b_vf3 = (const float*)d_in[11];
  P.w_jd1 = (const float*)d_in[12]; P.b_jd1 = (const float*)d_in[13];
  P.w_jd2 = (const float*)d_in[14]; P.b_jd2 = (const float*)d_in[15];
  P.w_kd1 = (const float*)d_in[16]; P.b_kd1 = (const float*)d_in[17];
  P.w_kd2 = (const float*)d_in[18]; P.b_kd2 = (const float*)d_in[19];
  P.w_sg  = (const float*)d_in[20]; P.b_sg  = (const float*)d_in[21];
  P.w_gs  = (const float*)d_in[22]; P.b_gs  = (const float*)d_in[23];
  P.w_glat= (const float*)d_in[24]; P.b_glat= (const float*)d_in[25];
  P.w_slat= (const float*)d_in[26]; P.b_slat= (const float*)d_in[27];
  P.w_d1gpi  = (const float*)d_in[28]; P.b_d1gpi  = (const float*)d_in[29];
  P.w_stngpi = (const float*)d_in[30]; P.b_stngpi = (const float*)d_in[31];
  P.w_ih = (const float*)d_in[32]; P.b_ih = (const float*)d_in[33];
  P.w_hh = (const float*)d_in[34]; P.b_hh = (const float*)d_in[35];
  P.wfrag = (const f16_t*)d_ws;
  P.out  = (float*)d_out;
  prep_frags<<<(NFRAG + 511) / 512, 512, 0, stream>>>(P.w_slat, P.w_sg, (f16_t*)d_ws);
  bg_main<<<NBLK, NTHR, 0, stream>>>(P);
}

// Round 9
// 411.077 us; speedup vs baseline: 1.4760x; 1.4760x over previous
//
#include <hip/hip_runtime.h>

// BasalGanglia fused kernel (MI355X / gfx950).
// R13: 16-wave single block (1024 thr, 4 waves/SIMD) — occupancy WITHIN the
// block, no streaming.
// Evidence chain: R11/R12 proved (a) 2nd launch_bounds arg = min-BLOCKS and
// sets both reg cap and residency ((512,4)->64regs+2blk; (512,2)->128regs+1blk);
// (b) streaming A-frags from L2 each iter is BW-infeasible (~480KB/CU-iter vs
// ~56B/cyc L2/CU) — R12 at 1blk = 518us vs R9's 316. Weights must stay in the
// distributed register file -> 2 blocks of 512 is impossible. Instead:
//  - NTHR=1024 (16 waves), BM=32, launch_bounds(1024,1): 16 waves/CU = 4/EU,
//    128-reg cap (proven-safe tier), occupancy ~50% in ONE block.
//  - 21 A-tiles over 16 waves: slot0 (t=0..15) in regs (40); slot1 tiles
//    16-20 in a 51KB LDS frag array read by waves 0-4 only -> uniform live
//    ~85-95 regs, no spill cliff. LDS ~145KB (1 block by design).
//  - Work remap: hh-gates waves 5-9; stngpi wave 10; LSTM waves 6-15 (=640 thr,
//    1 elem each); xgpe pack waves 3-4 (their slot1 = sg tiles).
//  - Keeps R9 wins: acc-carry 2*xstn, permuted whh (1-b128 LSTM gates), lstmc
//    pack, 3 barriers/iter, setprio around Phase-A MFMA.

typedef _Float16 f16_t;
typedef _Float16 f16x8 __attribute__((ext_vector_type(8)));
typedef _Float16 f16x4 __attribute__((ext_vector_type(4)));
typedef float floatx4 __attribute__((ext_vector_type(4)));
typedef float floatx2 __attribute__((ext_vector_type(2)));

#define BTOT 8192
#define BM   32
#define NTHR 1024
#define NBLK 256
#define VSTR 328   // f16 stride; dword-stride 164 -> uniform 8-lane bank groups
#define XST  32    // xgpe/hxf row stride (f16), k-pad zeroed

struct Params {
  const float *stimulus, *deltavf, *hx0, *cx0;
  const float *w_vf0, *b_vf0, *w_vf1, *b_vf1, *w_vf2, *b_vf2, *w_vf3, *b_vf3;
  const float *w_jd1, *b_jd1, *w_jd2, *b_jd2, *w_kd1, *b_kd1, *w_kd2, *b_kd2;
  const float *w_sg, *b_sg, *w_gs, *b_gs, *w_glat, *b_glat, *w_slat, *b_slat;
  const float *w_d1gpi, *b_d1gpi, *w_stngpi, *b_stngpi;
  const float *w_ih, *b_ih, *w_hh, *b_hh;
  float* out;
};

struct __align__(16) Smem {
  f16_t vstn[BM * VSTR];        // 20992 B
  f16_t xgpe[2][BM * XST];      // 4096 (double buffer)
  f16_t hxf[BM * XST];          // 2048
  f16_t wB2[21 * 512];          // 21504: t<19 gs-frag, t=19/20 glat-frag
  f16_t ws1[5 * 10 * 512];      // 51200: slot-1 A-frags (tiles 16-20), waves 0-4
  f16_t wsp[10 * 512];          // 10240: stngpi frags
  f16_t whh[5 * 512];           // 5120: w_hh gate frags (row-permuted r'=4j+g)
  union { float h1f[BM * 128]; float scr[3200]; float gates[BM * 80]; } u; // 16384
  float h0f[BM * 64];           // 8192
  float V_D2f[BM * 20];         // 2560
  float lstmc[20][12];          // 960
  float bsumS[304];             // b_slat+b_gs, pad->0
  float bsg[20];                // b_sg+b_glat
  float DPs[BM * 2], vgpis[BM * 2], lamS[BM];
};                              // ~146 KB -> 1 block/CU (by design)

__device__ __forceinline__ float rcp_f(float x) { return __builtin_amdgcn_rcpf(x); }
__device__ __forceinline__ float sigm_fast(float x) { return rcp_f(1.f + __expf(-x)); }
__device__ __forceinline__ float tanh_fast(float x) { return 1.f - 2.f * rcp_f(1.f + __expf(2.f * x)); }

// 8 f32 weights row[k0..k0+7] -> f16x8, zero for k>=kmax or !valid (4-granular).
__device__ __forceinline__ f16x8 ldfrag(const float* row, int k0, int kmax, bool valid) {
  float4 z = make_float4(0.f, 0.f, 0.f, 0.f);
  int nv = valid ? (kmax - k0) : 0;
  float4 f0 = (nv >= 4) ? *(const float4*)(row + k0) : z;
  float4 f1 = (nv >= 8) ? *(const float4*)(row + k0 + 4) : z;
  f16x8 r;
  r[0] = (f16_t)f0.x; r[1] = (f16_t)f0.y; r[2] = (f16_t)f0.z; r[3] = (f16_t)f0.w;
  r[4] = (f16_t)f1.x; r[5] = (f16_t)f1.y; r[6] = (f16_t)f1.z; r[7] = (f16_t)f1.w;
  return r;
}

__global__ __launch_bounds__(NTHR, 1) void bg_main(Params P) {
  __shared__ Smem S;
  const int tid  = threadIdx.x;
  const int lane = tid & 63;
  const int wv   = tid >> 6;          // 0..15
  const int q    = lane >> 4;
  const int cl   = lane & 15;
  const int row0 = blockIdx.x * BM;
  const floatx4 zf = {0.f, 0.f, 0.f, 0.f};

  // ---- slot map: slot0 = tile wv (regs); slot1 = tile 16+wv for wv<5 (LDS) --
  const bool has1  = (wv < 5);
  const bool isSgW = (wv == 3 || wv == 4);   // slot1 is sg tile (19/20)
  const int  gtile = (wv >= 5 && wv < 10) ? (wv - 5) : -1;  // hh-gate tiles

  // ================= init + LDS weight-frag staging =================
  if (tid < BM) S.lamS[tid] = sigm_fast(P.deltavf[row0 + tid]);
  for (int i = tid; i < BM * 2; i += NTHR) S.vgpis[i] = 0.f;
  for (int i = tid; i < 2 * BM * XST; i += NTHR) ((f16_t*)S.xgpe)[i] = (f16_t)0.f;
  for (int i = tid; i < BM * XST; i += NTHR) {
    int m = i >> 5, j = i & 31;
    S.hxf[i] = (j < 20) ? (f16_t)P.hx0[(size_t)(row0 + m) * 20 + j] : (f16_t)0.f;
  }
  for (int i = tid; i < BM * VSTR; i += NTHR) S.vstn[i] = (f16_t)0.f;
  for (int i = tid; i < 21 * 512; i += NTHR) {        // gs / glat frags
    int t = i >> 9, l = (i >> 3) & 63, jj = i & 7;
    int c2 = l & 15, k = ((l >> 4) << 3) + jj;
    float v = 0.f;
    if (t < 19) { int n = t * 16 + c2; if (n < 300 && k < 20) v = P.w_gs[n * 20 + k]; }
    else        { int g = (t - 19) * 16 + c2; if (g < 20 && k < 20) v = P.w_glat[g * 20 + k]; }
    S.wB2[i] = (f16_t)v;
  }
  for (int i = tid; i < 5 * 5120; i += NTHR) {        // slot-1 A-frags (t=16..20)
    int t5 = i / 5120, rem = i - t5 * 5120;
    int c = rem >> 9, l = (rem >> 3) & 63, jj = i & 7;
    int c2 = l & 15, k = c * 32 + ((l >> 4) << 3) + jj;
    int t = 16 + t5;
    float v = 0.f;
    if (t < 19) { int n = t * 16 + c2; if (n < 300 && k < 300) v = P.w_slat[(size_t)n * 300 + k]; }
    else        { int g = (t - 19) * 16 + c2; if (g < 20 && k < 300) v = P.w_sg[(size_t)g * 300 + k]; }
    S.ws1[i] = (f16_t)v;
  }
  for (int i = tid; i < 10 * 512; i += NTHR) {        // stngpi frags
    int c = i >> 9, l = (i >> 3) & 63, jj = i & 7;
    int p = l & 15, k = c * 32 + ((l >> 4) << 3) + jj;
    float v = (p < 2 && k < 300) ? P.w_stngpi[p * 300 + k] : 0.f;
    S.wsp[i] = (f16_t)v;
  }
  for (int i = tid; i < 5 * 512; i += NTHR) {         // w_hh gate frags, PERMUTED
    int t = i >> 9, l = (i >> 3) & 63, jj = i & 7;
    int c2 = l & 15, k = ((l >> 4) << 3) + jj;
    int orig = (c2 & 3) * 20 + 4 * t + (c2 >> 2);     // r'=4j+g -> orig g*20+j
    S.whh[i] = (f16_t)((k < 20) ? P.w_hh[orig * 20 + k] : 0.f);
  }
  for (int i = tid; i < 240; i += NTHR) {             // LSTM consts [j][12]
    int j = i / 12, c = i - j * 12;
    float v;
    if (c < 4)      v = P.b_ih[c * 20 + j] + P.b_hh[c * 20 + j];
    else if (c < 8) v = P.w_ih[((c - 4) * 20 + j) * 2 + 0];
    else            v = P.w_ih[((c - 8) * 20 + j) * 2 + 1];
    S.lstmc[j][c] = v;
  }
  for (int i = tid; i < 304; i += NTHR) S.bsumS[i] = (i < 300) ? (P.b_slat[i] + P.b_gs[i]) : 0.f;
  for (int i = tid; i < 20; i += NTHR)  S.bsg[i] = P.b_sg[i] + P.b_glat[i];

  { // h0 = relu(stim @ w_vf0^T + b): 32 rows x 64 out; 2 rows/thread (16 grp)
    int o = tid & 63, mb = (tid >> 6) * 2;
    const float4* wr = (const float4*)(P.w_vf0 + o * 300);
    float bias = P.b_vf0[o], a[2];
    a[0] = bias; a[1] = bias;
    for (int kq = 0; kq < 75; ++kq) {
      float4 w = wr[kq];
#pragma unroll
      for (int u = 0; u < 2; ++u) {
        float4 v = *(const float4*)(P.stimulus + (size_t)(row0 + mb + u) * 300 + kq * 4);
        a[u] = fmaf(v.x, w.x, a[u]); a[u] = fmaf(v.y, w.y, a[u]);
        a[u] = fmaf(v.z, w.z, a[u]); a[u] = fmaf(v.w, w.w, a[u]);
      }
    }
#pragma unroll
    for (int u = 0; u < 2; ++u) S.h0f[(mb + u) * 64 + o] = fmaxf(a[u], 0.f);
  }
  __syncthreads();
  { // h1: 32 x 128; 4 rows/thread (8 grp)
    int o = tid & 127, mb = (tid >> 7) * 4;
    const float* wr = P.w_vf1 + o * 64;
    float bias = P.b_vf1[o], a[4];
#pragma unroll
    for (int u = 0; u < 4; ++u) a[u] = bias;
    for (int k = 0; k < 64; ++k) {
      float w = wr[k];
#pragma unroll
      for (int u = 0; u < 4; ++u) a[u] = fmaf(S.h0f[(mb + u) * 64 + k], w, a[u]);
    }
#pragma unroll
    for (int u = 0; u < 4; ++u) S.u.h1f[(mb + u) * 128 + o] = fmaxf(a[u], 0.f);
  }
  __syncthreads();
  { // h2 -> h0f: 32 x 64; 2 rows/thread
    int o = tid & 63, mb = (tid >> 6) * 2;
    const float* wr = P.w_vf2 + o * 128;
    float bias = P.b_vf2[o], a[2];
    a[0] = bias; a[1] = bias;
    for (int k = 0; k < 128; ++k) {
      float w = wr[k];
#pragma unroll
      for (int u = 0; u < 2; ++u) a[u] = fmaf(S.u.h1f[(mb + u) * 128 + k], w, a[u]);
    }
#pragma unroll
    for (int u = 0; u < 2; ++u) S.h0f[(mb + u) * 64 + o] = fmaxf(a[u], 0.f);
  }
  __syncthreads();
  { // drives -> scr[0:2560); vt output
    int oid = tid & 127, mb = (tid >> 7) * 4;
    if (oid < 80) {
      int which = oid / 20, o = oid - which * 20;
      const float *wp, *bp;
      if (which == 0)      { wp = P.w_jd1; bp = P.b_jd1; }
      else if (which == 1) { wp = P.w_jd2; bp = P.b_jd2; }
      else if (which == 2) { wp = P.w_kd1; bp = P.b_kd1; }
      else                 { wp = P.w_kd2; bp = P.b_kd2; }
      float bias = bp[o], a[4];
#pragma unroll
      for (int u = 0; u < 4; ++u) a[u] = bias;
      for (int kq = 0; kq < 75; ++kq) {
        float4 w = *(const float4*)(wp + o * 300 + kq * 4);
#pragma unroll
        for (int u = 0; u < 4; ++u) {
          float4 v = *(const float4*)(P.stimulus + (size_t)(row0 + mb + u) * 300 + kq * 4);
          a[u] = fmaf(v.x, w.x, a[u]); a[u] = fmaf(v.y, w.y, a[u]);
          a[u] = fmaf(v.z, w.z, a[u]); a[u] = fmaf(v.w, w.w, a[u]);
        }
      }
#pragma unroll
      for (int u = 0; u < 4; ++u) S.u.scr[which * 640 + (mb + u) * 20 + o] = a[u];
    }
    if (tid < BM) {
      float a = P.b_vf3[0];
      for (int k = 0; k < 64; ++k) a = fmaf(S.h0f[tid * 64 + k], P.w_vf3[k], a);
      P.out[(size_t)BTOT * 20 + row0 + tid] = tanh_fast(a);
    }
  }
  __syncthreads();
  for (int i = tid; i < BM * 20; i += NTHR) { // FF -> V_D1 scr[2560:), V_D2f
    int m = i / 20;
    float j1 = S.u.scr[i],        j2 = S.u.scr[640 + i];
    float k1 = S.u.scr[1280 + i], k2 = S.u.scr[1920 + i];
    float L = S.lamS[m], v1 = 0.f, v2 = 0.f;
    for (int s = 0; s < 20; ++s) {
      v1 = sigm_fast(L * (j1 * (1.f - v1) + (1.f - k1) * v1));
      v2 = sigm_fast(L * (j2 * (1.f - v2) + (1.f - k2) * v2));
    }
    S.u.scr[2560 + i] = v1;
    S.V_D2f[i] = v2;
  }
  __syncthreads();
  if (tid < BM * 2) { // V_GPi_DP
    int m = tid >> 1, p2 = tid & 1;
    float a = P.b_d1gpi[p2];
    for (int o = 0; o < 20; ++o) a = fmaf(S.u.scr[2560 + m * 20 + o], P.w_d1gpi[p2 * 20 + o], a);
    S.DPs[tid] = a;
  }
  __syncthreads();

  // ---- slot0 A-frags (tile = wv, always a valid slat tile 0..15) in regs ----
  f16x8 Ws0[10];
  {
    int n = wv * 16 + cl;    // <= 255 < 300, always valid
    const float* a0 = P.w_slat + (size_t)n * 300;
#pragma unroll
    for (int c = 0; c < 10; ++c) Ws0[c] = ldfrag(a0, c * 32 + q * 8, 300, true);
  }
  const float lam0 = S.lamS[cl], lam1 = S.lamS[cl + 16];
  const float bstn0 = P.b_stngpi[0], bstn1 = P.b_stngpi[1];
  // LSTM: waves 6-15 (tid in [384,1024)) own elem e = tid-384 of 640.
  const bool lown = (tid >= 384);
  const int  e0 = lown ? (tid - 384) : 0;
  const int  m0 = e0 / 20, j0 = e0 - m0 * 20;
  float cxr0 = lown ? P.cx0[(size_t)row0 * 20 + e0] : 0.f;
  float hxr0 = 0.f;

  // acc carries 2*xstn across iterations; [slot][mf]. sg slot re-zeroed.
  floatx4 acc[2][2];
  acc[0][0] = zf; acc[0][1] = zf; acc[1][0] = zf; acc[1][1] = zf;

  // ================= STN recurrence, 50 iterations, 3 barriers/iter =========
  for (int it = 0; it < 50; ++it) {
    const int po = it & 1, pn = po ^ 1;
    if (isSgW) { acc[1][0] = zf; acc[1][1] = zf; }   // sg slot fresh each iter

    // ---- Phase A: acc += [slat|sg] @ vstn^T (+ glat @ xgpe_old^T, pack) ----
    __builtin_amdgcn_s_setprio(1);
    if (has1) {
#pragma unroll
      for (int c = 0; c < 10; ++c) {
        f16x8 b0 = *(const f16x8*)&S.vstn[cl * VSTR + c * 32 + q * 8];
        f16x8 b1 = *(const f16x8*)&S.vstn[(16 + cl) * VSTR + c * 32 + q * 8];
        f16x8 a1 = *(const f16x8*)&S.ws1[(wv * 10 + c) * 512 + lane * 8];
        acc[0][0] = __builtin_amdgcn_mfma_f32_16x16x32_f16(Ws0[c], b0, acc[0][0], 0, 0, 0);
        acc[0][1] = __builtin_amdgcn_mfma_f32_16x16x32_f16(Ws0[c], b1, acc[0][1], 0, 0, 0);
        acc[1][0] = __builtin_amdgcn_mfma_f32_16x16x32_f16(a1, b0, acc[1][0], 0, 0, 0);
        acc[1][1] = __builtin_amdgcn_mfma_f32_16x16x32_f16(a1, b1, acc[1][1], 0, 0, 0);
      }
    } else {
#pragma unroll
      for (int c = 0; c < 10; ++c) {
        f16x8 b0 = *(const f16x8*)&S.vstn[cl * VSTR + c * 32 + q * 8];
        f16x8 b1 = *(const f16x8*)&S.vstn[(16 + cl) * VSTR + c * 32 + q * 8];
        acc[0][0] = __builtin_amdgcn_mfma_f32_16x16x32_f16(Ws0[c], b0, acc[0][0], 0, 0, 0);
        acc[0][1] = __builtin_amdgcn_mfma_f32_16x16x32_f16(Ws0[c], b1, acc[0][1], 0, 0, 0);
      }
    }
    __builtin_amdgcn_s_setprio(0);
    if (isSgW) { // waves 3/4: finish xgpe update via glat, pack to LDS
      f16x8 Wg = *(const f16x8*)&S.wB2[(16 + wv) * 512 + lane * 8];   // t=19/20
      f16x8 g0 = *(const f16x8*)&S.xgpe[po][cl * XST + q * 8];
      f16x8 g1 = *(const f16x8*)&S.xgpe[po][(16 + cl) * XST + q * 8];
      acc[1][0] = __builtin_amdgcn_mfma_f32_16x16x32_f16(Wg, g0, acc[1][0], 0, 0, 0);
      acc[1][1] = __builtin_amdgcn_mfma_f32_16x16x32_f16(Wg, g1, acc[1][1], 0, 0, 0);
      int g0i = (wv - 3) * 16 + q * 4;
      if (g0i < 20) {
        floatx4 bg4 = *(const floatx4*)&S.bsg[g0i];
#pragma unroll
        for (int mf = 0; mf < 2; ++mf) {
          int batch = cl + 16 * mf;
          floatx4 vd4 = *(const floatx4*)&S.V_D2f[batch * 20 + g0i];
          f16x4 pk;
#pragma unroll
          for (int r = 0; r < 4; ++r) pk[r] = (f16_t)(acc[1][mf][r] + bg4[r] - vd4[r]);
          *(f16x4*)&S.xgpe[pn][batch * XST + g0i] = pk;
        }
      }
    }
    __syncthreads(); // b1: xgpe_new ready

    // ---- Phase B: acc += gs @ xgpe_new^T; hh-gates; xstn/vstn update ----
    {
      f16x8 x0 = *(const f16x8*)&S.xgpe[pn][cl * XST + q * 8];
      f16x8 x1 = *(const f16x8*)&S.xgpe[pn][(16 + cl) * XST + q * 8];
      if (gtile >= 0) { // hh-gates (permuted rows): gates[batch][4j+g]
        f16x8 Wh = *(const f16x8*)&S.whh[gtile * 512 + lane * 8];
        f16x8 h0 = *(const f16x8*)&S.hxf[cl * XST + q * 8];
        f16x8 h1 = *(const f16x8*)&S.hxf[(16 + cl) * XST + q * 8];
        floatx4 gA = __builtin_amdgcn_mfma_f32_16x16x32_f16(Wh, h0, zf, 0, 0, 0);
        floatx4 gB = __builtin_amdgcn_mfma_f32_16x16x32_f16(Wh, h1, zf, 0, 0, 0);
        int gb = gtile * 16 + q * 4;
        *(floatx4*)&S.u.gates[cl * 80 + gb] = gA;
        *(floatx4*)&S.u.gates[(cl + 16) * 80 + gb] = gB;
      }
#pragma unroll
      for (int j = 0; j < 2; ++j) {
        int t = j ? (has1 ? 16 + wv : 99) : wv;   // slot tiles
        if (t < 19) {
          f16x8 Wg = *(const f16x8*)&S.wB2[t * 512 + lane * 8];
          acc[j][0] = __builtin_amdgcn_mfma_f32_16x16x32_f16(Wg, x0, acc[j][0], 0, 0, 0);
          acc[j][1] = __builtin_amdgcn_mfma_f32_16x16x32_f16(Wg, x1, acc[j][1], 0, 0, 0);
        }
      }
#pragma unroll
      for (int j = 0; j < 2; ++j) {
        int t = j ? (has1 ? 16 + wv : 99) : wv;
        if (t < 19) {
          int n0 = t * 16 + q * 4;
          if (!(t == 18 && q == 3)) {  // n0..n0+3 all < 300
            floatx4 bs4 = *(const floatx4*)&S.bsumS[n0];
#pragma unroll
            for (int mf = 0; mf < 2; ++mf) {
              float lm = mf ? lam1 : lam0;
              f16x4 pk;
#pragma unroll
              for (int r = 0; r < 4; ++r) {
                float tmp = acc[j][mf][r] + bs4[r];      // = 2*xo + W.v + bs
                float xn  = tmp * (1.0f / 3.0f);         // new xstn
                acc[j][mf][r] = tmp * (2.0f / 3.0f);     // carry 2*xn
                pk[r] = (f16_t)tanh_fast(lm * xn);
              }
              *(f16x4*)&S.vstn[(cl + 16 * mf) * VSTR + n0] = pk;
            }
          }
        }
      }
    }
    __syncthreads(); // b2: vstn_new + gates ready

    // ---- Phase C: wave 10 stngpi -> vgpi ----
    if (wv == 10) {
      floatx4 ip0 = zf, ip1 = zf;
#pragma unroll
      for (int c = 0; c < 10; ++c) {
        f16x8 Wp = *(const f16x8*)&S.wsp[c * 512 + lane * 8];
        f16x8 b0 = *(const f16x8*)&S.vstn[cl * VSTR + c * 32 + q * 8];
        f16x8 b1 = *(const f16x8*)&S.vstn[(16 + cl) * VSTR + c * 32 + q * 8];
        ip0 = __builtin_amdgcn_mfma_f32_16x16x32_f16(Wp, b0, ip0, 0, 0, 0);
        ip1 = __builtin_amdgcn_mfma_f32_16x16x32_f16(Wp, b1, ip1, 0, 0, 0);
      }
      if (q == 0) {
#pragma unroll
        for (int mf = 0; mf < 2; ++mf) {
          int batch = cl + 16 * mf;
          float lm = mf ? lam1 : lam0;
          floatx2 vg = *(const floatx2*)&S.vgpis[batch * 2];
          floatx2 dp = *(const floatx2*)&S.DPs[batch * 2];
          float ipa = lm * ((mf ? ip1[0] : ip0[0]) + bstn0);
          float ipb = lm * ((mf ? ip1[1] : ip0[1]) + bstn1);
          vg[0] = vg[0] + 0.1f * (-vg[0] - dp[0] + 2.f * ipa);
          vg[1] = vg[1] + 0.1f * (-vg[1] - dp[1] + 2.f * ipb);
          *(floatx2*)&S.vgpis[batch * 2] = vg;
        }
      }
    }
    __syncthreads(); // b3: vgpis ready

    // ---- Phase D: LSTM pointwise on waves 6-15 (1 elem/thread) ----
    if (lown) {
      floatx4 g4 = *(const floatx4*)&S.u.gates[m0 * 80 + j0 * 4];
      floatx4 cb = *(const floatx4*)&S.lstmc[j0][0];
      floatx4 w0 = *(const floatx4*)&S.lstmc[j0][4];
      floatx4 w1 = *(const floatx4*)&S.lstmc[j0][8];
      floatx2 vg = *(const floatx2*)&S.vgpis[m0 * 2];
      float gi = g4[0] + cb[0] - w0[0] * vg[0] - w1[0] * vg[1];
      float gf = g4[1] + cb[1] - w0[1] * vg[0] - w1[1] * vg[1];
      float gg = g4[2] + cb[2] - w0[2] * vg[0] - w1[2] * vg[1];
      float go = g4[3] + cb[3] - w0[3] * vg[0] - w1[3] * vg[1];
      float cn = sigm_fast(gf) * cxr0 + sigm_fast(gi) * tanh_fast(gg);
      cxr0 = cn;
      hxr0 = sigm_fast(go) * tanh_fast(cn);
      S.hxf[m0 * XST + j0] = (f16_t)hxr0;
    }
    // no b4: D writes hxf (next reader B's hh, after next b1); D reads
    // gates/vgpis (next writers B/C, after next b1/b2). Next A touches only
    // vstn/xgpe/Ws (ordered by b2/b1).
  }

  // ---- output hx from registers ----
  if (lown) P.out[(size_t)row0 * 20 + e0] = hxr0;
}

extern "C" void kernel_launch(void* const* d_in, const int* in_sizes, int n_in,
                              void* d_out, int out_size, void* d_ws, size_t ws_size,
                              hipStream_t stream) {
  (void)in_sizes; (void)n_in; (void)out_size; (void)d_ws; (void)ws_size;
  Params P;
  P.stimulus = (const float*)d_in[0];
  P.deltavf  = (const float*)d_in[1];
  P.hx0 = (const float*)d_in[2];
  P.cx0 = (const float*)d_in[3];
  P.w_vf0 = (const float*)d_in[4];  P.b_vf0 = (const float*)d_in[5];
  P.w_vf1 = (const float*)d_in[6];  P.b_vf1 = (const float*)d_in[7];
  P.w_vf2 = (const float*)d_in[8];  P.b_vf2 = (const float*)d_in[9];
  P.w_vf3 = (const float*)d_in[10]; P.b_vf3 = (const float*)d_in[11];
  P.w_jd1 = (const float*)d_in[12]; P.b_jd1 = (const float*)d_in[13];
  P.w_jd2 = (const float*)d_in[14]; P.b_jd2 = (const float*)d_in[15];
  P.w_kd1 = (const float*)d_in[16]; P.b_kd1 = (const float*)d_in[17];
  P.w_kd2 = (const float*)d_in[18]; P.b_kd2 = (const float*)d_in[19];
  P.w_sg  = (const float*)d_in[20]; P.b_sg  = (const float*)d_in[21];
  P.w_gs  = (const float*)d_in[22]; P.b_gs  = (const float*)d_in[23];
  P.w_glat= (const float*)d_in[24]; P.b_glat= (const float*)d_in[25];
  P.w_slat= (const float*)d_in[26]; P.b_slat= (const float*)d_in[27];
  P.w_d1gpi  = (const float*)d_in[28]; P.b_d1gpi  = (const float*)d_in[29];
  P.w_stngpi = (const float*)d_in[30]; P.b_stngpi = (const float*)d_in[31];
  P.w_ih = (const float*)d_in[32]; P.b_ih = (const float*)d_in[33];
  P.w_hh = (const float*)d_in[34]; P.b_hh = (const float*)d_in[35];
  P.out  = (float*)d_out;
  bg_main<<<NBLK, NTHR, 0, stream>>>(P);
}